// Round 1
// baseline (406.369 us; speedup 1.0000x reference)
//
#include <hip/hip_runtime.h>
#include <stdint.h>

// Problem constants (from reference setup_inputs)
#define T_TOK 1024
#define K_IN  4096
#define N_OUT 6144
#define N_Q   4096
#define N_KV  1024
#define N_D   4
#define KP    512          // K_IN/8 packed int32 per row

// GEMM tiling
#define TM 128
#define TN 128
#define BK 64
#define PM_MAX 1536        // >= 1024 + 4*127 rounded up; fixed grid bound
#define MT (PM_MAX/TM)     // 12
#define NT (N_OUT/TN)      // 48

typedef __attribute__((ext_vector_type(8)))  short  short8;   // 8 x bf16 (4 VGPR) MFMA A/B frag
typedef __attribute__((ext_vector_type(4)))  float  float4v;  // MFMA C/D frag

__device__ __forceinline__ ushort f2bf(float f) {
    uint32_t u = __float_as_uint(f);
    u = (u + 0x7FFFu + ((u >> 16) & 1u)) >> 16;   // RNE
    return (ushort)u;
}
__device__ __forceinline__ uint pack2(ushort a, ushort b) {
    return (uint)a | ((uint)b << 16);
}

// ---------------------------------------------------------------------------
// K1: group tokens by adapter. perm[PM_MAX] = token index or -1 (padding);
// pofs[d] = padded segment starts (multiples of TM), pofs[N_D] = padded total.
// ---------------------------------------------------------------------------
__global__ void build_perm_kernel(const int* __restrict__ indices,
                                  int* __restrict__ perm,
                                  int* __restrict__ pofs) {
    __shared__ int cnt[N_D], cur[N_D], ps[N_D + 1];
    int tid = threadIdx.x;
    if (tid < N_D) { cnt[tid] = 0; cur[tid] = 0; }
    __syncthreads();
    for (int t = tid; t < T_TOK; t += blockDim.x) atomicAdd(&cnt[indices[t]], 1);
    for (int p = tid; p < PM_MAX; p += blockDim.x) perm[p] = -1;
    __syncthreads();
    if (tid == 0) {
        int run = 0;
        for (int d = 0; d < N_D; d++) { ps[d] = run; run += ((cnt[d] + TM - 1) / TM) * TM; }
        ps[N_D] = run;
        for (int d = 0; d <= N_D; d++) pofs[d] = ps[d];
    }
    __syncthreads();
    for (int t = tid; t < T_TOK; t += blockDim.x) {
        int d = indices[t];
        int r = atomicAdd(&cur[d], 1);
        perm[ps[d] + r] = t;   // slot order arbitrary; per-token result independent of slot
    }
}

// ---------------------------------------------------------------------------
// K2: W_all[d][o][k] = bf16( w_base[o][k] + (nib(qw)- (nib(qz)+1)) * scale )
// One thread per packed int32 -> 8 bf16 (16B store).
// ---------------------------------------------------------------------------
__global__ void dequant_wall_kernel(const float* __restrict__ w_base,
                                    const int* __restrict__ qw_q, const int* __restrict__ qw_k, const int* __restrict__ qw_v,
                                    const int* __restrict__ qz_q, const int* __restrict__ qz_k, const int* __restrict__ qz_v,
                                    const float* __restrict__ sc_q, const float* __restrict__ sc_k, const float* __restrict__ sc_v,
                                    ushort* __restrict__ wall) {
    int id  = blockIdx.x * blockDim.x + threadIdx.x;   // [0, N_D*N_OUT*KP)
    int kq  = id & (KP - 1);
    int oid = id >> 9;          // KP = 512
    int o   = oid % N_OUT;
    int d   = oid / N_OUT;

    const int* qw; const int* qz; const float* sc; int r, Osec;
    if (o < N_Q)            { qw = qw_q; qz = qz_q; sc = sc_q; r = o;                Osec = N_Q;  }
    else if (o < N_Q + N_KV){ qw = qw_k; qz = qz_k; sc = sc_k; r = o - N_Q;          Osec = N_KV; }
    else                    { qw = qw_v; qz = qz_v; sc = sc_v; r = o - (N_Q + N_KV); Osec = N_KV; }

    int   q  = qw[((size_t)d * Osec + r) * KP + kq];
    int   zq = qz[(size_t)d * (Osec / 8) + (r >> 3)];
    float s  = sc[(size_t)d * Osec + r];
    float zs = (float)(((zq >> ((r & 7) * 4)) & 0xF) + 1) * s;

    const float* wb = w_base + (size_t)o * K_IN + (size_t)kq * 8;
    ushort res[8];
#pragma unroll
    for (int j = 0; j < 8; j++) {
        float v = wb[j] + (float)((q >> (4 * j)) & 0xF) * s - zs;
        res[j] = f2bf(v);
    }
    uint4 packv;
    packv.x = pack2(res[0], res[1]); packv.y = pack2(res[2], res[3]);
    packv.z = pack2(res[4], res[5]); packv.w = pack2(res[6], res[7]);
    *(uint4*)(wall + ((size_t)d * N_OUT + o) * K_IN + (size_t)kq * 8) = packv;
}

// ---------------------------------------------------------------------------
// K3: Xp[pm][k] = bf16(x[perm[pm]][k]) or 0 for padding rows.
// grid (PM_MAX, 2), 256 threads, 8 elems/thread.
// ---------------------------------------------------------------------------
__global__ void build_xp_kernel(const float* __restrict__ x,
                                const int* __restrict__ perm,
                                ushort* __restrict__ xp) {
    int pm = blockIdx.x;
    int c0 = blockIdx.y * 2048 + threadIdx.x * 8;
    int tok = perm[pm];
    ushort res[8];
    if (tok < 0) {
#pragma unroll
        for (int j = 0; j < 8; j++) res[j] = 0;
    } else {
        const float* src = x + (size_t)tok * K_IN + c0;
#pragma unroll
        for (int j = 0; j < 8; j++) res[j] = f2bf(src[j]);
    }
    uint4 packv;
    packv.x = pack2(res[0], res[1]); packv.y = pack2(res[2], res[3]);
    packv.z = pack2(res[4], res[5]); packv.w = pack2(res[6], res[7]);
    *(uint4*)(xp + (size_t)pm * K_IN + c0) = packv;
}

// ---------------------------------------------------------------------------
// K4: fused GEMM. out[perm[m]][n] = Xp[m] @ W_all[d(m)][n][:] + bias[n]
// m97-style: 128x128 tile, BK=64, global_load_lds(16B) staging, 4 waves
// each computing a 64x64 quadrant via 4x4 of 16x16x32 bf16 MFMA.
// ---------------------------------------------------------------------------
__global__ __launch_bounds__(256, 2) void gemm_kernel(
    const ushort* __restrict__ xp, const ushort* __restrict__ wall,
    const int* __restrict__ perm, const int* __restrict__ pofs,
    const float* __restrict__ bias, float* __restrict__ out) {

    __shared__ ushort As[TM * BK];   // 16 KB
    __shared__ ushort Bs[TN * BK];   // 16 KB

    int bn = blockIdx.x, bm = blockIdx.y;
    int m0 = bm * TM, n0 = bn * TN;
    int ptot = pofs[N_D];
    if (m0 >= ptot) return;                       // uniform per block
    int d = 0;
    while (d < N_D - 1 && m0 >= pofs[d + 1]) d++; // tile fully inside segment d

    const ushort* wsec = wall + (size_t)d * N_OUT * K_IN;

    int tid  = threadIdx.x;
    int lane = tid & 63;
    int wv   = tid >> 6;
    int wm   = (wv & 1) * 64;
    int wn   = (wv >> 1) * 64;
    int quad = lane >> 4;
    int l16  = lane & 15;

    const float4v zero4 = {0.f, 0.f, 0.f, 0.f};
    float4v acc[4][4];
#pragma unroll
    for (int i = 0; i < 4; i++)
#pragma unroll
        for (int j = 0; j < 4; j++) acc[i][j] = zero4;

    for (int k0 = 0; k0 < K_IN; k0 += BK) {
        // stage A (Xp rows m0..m0+127) and B (W_all rows n0..n0+127), 16B/lane
#pragma unroll
        for (int w = 0; w < 4; w++) {
            int c   = w * 256 + tid;        // chunk id: row = c>>3, 16B-col = c&7
            int row = c >> 3, ck = c & 7;
            const ushort* ga = xp   + (size_t)(m0 + row) * K_IN + k0 + ck * 8;
            const ushort* gb = wsec + (size_t)(n0 + row) * K_IN + k0 + ck * 8;
            int base = (w * 256 + (tid & ~63)) * 8;   // wave-uniform ushort offset
            __builtin_amdgcn_global_load_lds((const __attribute__((address_space(1))) void*)ga,
                                             (__attribute__((address_space(3))) void*)(As + base), 16, 0, 0);
            __builtin_amdgcn_global_load_lds((const __attribute__((address_space(1))) void*)gb,
                                             (__attribute__((address_space(3))) void*)(Bs + base), 16, 0, 0);
        }
        __syncthreads();

#pragma unroll
        for (int kk = 0; kk < BK; kk += 32) {
            short8 a[4], b[4];
#pragma unroll
            for (int i = 0; i < 4; i++)
                a[i] = *(const short8*)(As + (wm + i * 16 + l16) * BK + kk + quad * 8);
#pragma unroll
            for (int j = 0; j < 4; j++)
                b[j] = *(const short8*)(Bs + (wn + j * 16 + l16) * BK + kk + quad * 8);
#pragma unroll
            for (int i = 0; i < 4; i++)
#pragma unroll
                for (int j = 0; j < 4; j++)
                    acc[i][j] = __builtin_amdgcn_mfma_f32_16x16x32_bf16(a[i], b[j], acc[i][j], 0, 0, 0);
        }
        __syncthreads();
    }

    // epilogue: C/D layout col = lane&15, row = quad*4 + reg  [m89/m91 verified]
#pragma unroll
    for (int i = 0; i < 4; i++) {
        int toks[4];
#pragma unroll
        for (int r = 0; r < 4; r++) toks[r] = perm[m0 + wm + i * 16 + quad * 4 + r];
#pragma unroll
        for (int j = 0; j < 4; j++) {
            int col = n0 + wn + j * 16 + l16;
            float bv = bias[col];
#pragma unroll
            for (int r = 0; r < 4; r++) {
                int tok = toks[r];
                if (tok >= 0) out[(size_t)tok * N_OUT + col] = acc[i][j][r] + bv;
            }
        }
    }
}

// ---------------------------------------------------------------------------
extern "C" void kernel_launch(void* const* d_in, const int* in_sizes, int n_in,
                              void* d_out, int out_size, void* d_ws, size_t ws_size,
                              hipStream_t stream) {
    const float* x      = (const float*)d_in[0];
    const float* w_base = (const float*)d_in[1];
    const float* bias   = (const float*)d_in[2];
    const int*   qw_q   = (const int*)d_in[3];
    const int*   qw_k   = (const int*)d_in[4];
    const int*   qw_v   = (const int*)d_in[5];
    const int*   qz_q   = (const int*)d_in[6];
    const int*   qz_k   = (const int*)d_in[7];
    const int*   qz_v   = (const int*)d_in[8];
    const float* sc_q   = (const float*)d_in[9];
    const float* sc_k   = (const float*)d_in[10];
    const float* sc_v   = (const float*)d_in[11];
    const int*   indices= (const int*)d_in[12];
    float* out = (float*)d_out;

    // workspace layout: W_all bf16 [4][6144][4096] | Xp bf16 [1536][4096] | perm | pofs
    char* ws = (char*)d_ws;
    ushort* wall = (ushort*)ws;
    size_t wall_bytes = (size_t)N_D * N_OUT * K_IN * 2;          // 201326592
    ushort* xp = (ushort*)(ws + wall_bytes);
    size_t xp_bytes = (size_t)PM_MAX * K_IN * 2;                  // 12582912
    int* perm = (int*)(ws + wall_bytes + xp_bytes);
    int* pofs = perm + PM_MAX;

    build_perm_kernel<<<1, 256, 0, stream>>>(indices, perm, pofs);
    dequant_wall_kernel<<<(N_D * N_OUT * KP) / 256, 256, 0, stream>>>(
        w_base, qw_q, qw_k, qw_v, qz_q, qz_k, qz_v, sc_q, sc_k, sc_v, wall);
    build_xp_kernel<<<dim3(PM_MAX, 2), 256, 0, stream>>>(x, perm, xp);
    gemm_kernel<<<dim3(NT, MT), 256, 0, stream>>>(xp, wall, perm, pofs, bias, out);
}

// Round 2
// 376.908 us; speedup vs baseline: 1.0782x; 1.0782x over previous
//
#include <hip/hip_runtime.h>
#include <stdint.h>

// Problem constants (from reference setup_inputs)
#define T_TOK 1024
#define K_IN  4096
#define N_OUT 6144
#define N_Q   4096
#define N_KV  1024
#define N_D   4
#define KP    512          // K_IN/8 packed int32 per row

// GEMM tiling
#define TM 128
#define TN 128
#define BK 64
#define KSPLIT 2
#define KHALF (K_IN / KSPLIT)   // 2048
#define PM_MAX 1536        // >= 1024 + 4*127 rounded up; fixed grid bound
#define MT (PM_MAX/TM)     // 12
#define NT (N_OUT/TN)      // 48

typedef __attribute__((ext_vector_type(8)))  short  short8;   // 8 x bf16 (4 VGPR) MFMA A/B frag
typedef __attribute__((ext_vector_type(4)))  float  float4v;  // MFMA C/D frag

__device__ __forceinline__ ushort f2bf(float f) {
    uint32_t u = __float_as_uint(f);
    u = (u + 0x7FFFu + ((u >> 16) & 1u)) >> 16;   // RNE
    return (ushort)u;
}
__device__ __forceinline__ uint pack2(ushort a, ushort b) {
    return (uint)a | ((uint)b << 16);
}

// ---------------------------------------------------------------------------
// K1: group tokens by adapter. perm[PM_MAX] = token index or -1 (padding);
// pofs[d] = padded segment starts (multiples of TM), pofs[N_D] = padded total.
// ---------------------------------------------------------------------------
__global__ void build_perm_kernel(const int* __restrict__ indices,
                                  int* __restrict__ perm,
                                  int* __restrict__ pofs) {
    __shared__ int cnt[N_D], cur[N_D], ps[N_D + 1];
    int tid = threadIdx.x;
    if (tid < N_D) { cnt[tid] = 0; cur[tid] = 0; }
    __syncthreads();
    for (int t = tid; t < T_TOK; t += blockDim.x) atomicAdd(&cnt[indices[t]], 1);
    for (int p = tid; p < PM_MAX; p += blockDim.x) perm[p] = -1;
    __syncthreads();
    if (tid == 0) {
        int run = 0;
        for (int d = 0; d < N_D; d++) { ps[d] = run; run += ((cnt[d] + TM - 1) / TM) * TM; }
        ps[N_D] = run;
        for (int d = 0; d <= N_D; d++) pofs[d] = ps[d];
    }
    __syncthreads();
    for (int t = tid; t < T_TOK; t += blockDim.x) {
        int d = indices[t];
        int r = atomicAdd(&cur[d], 1);
        perm[ps[d] + r] = t;   // slot order arbitrary; per-token result independent of slot
    }
}

// ---------------------------------------------------------------------------
// K2: W_all[d][o][k] = bf16( w_base[o][k] + (nib(qw)- (nib(qz)+1)) * scale )
// One thread per (o, kq) handles ALL 4 adapters: w_base read ONCE (was 4x).
// Traffic: 100 MB wb + 50 MB qw + 201 MB write = 351 MB (was ~650 MB).
// ---------------------------------------------------------------------------
__global__ void dequant_wall_kernel(const float* __restrict__ w_base,
                                    const int* __restrict__ qw_q, const int* __restrict__ qw_k, const int* __restrict__ qw_v,
                                    const int* __restrict__ qz_q, const int* __restrict__ qz_k, const int* __restrict__ qz_v,
                                    const float* __restrict__ sc_q, const float* __restrict__ sc_k, const float* __restrict__ sc_v,
                                    ushort* __restrict__ wall) {
    int id  = blockIdx.x * blockDim.x + threadIdx.x;   // [0, N_OUT*KP)
    int kq  = id & (KP - 1);
    int o   = id >> 9;          // KP = 512; block-uniform (256 | 512)

    const int* qw; const int* qz; const float* sc; int r, Osec;
    if (o < N_Q)            { qw = qw_q; qz = qz_q; sc = sc_q; r = o;                Osec = N_Q;  }
    else if (o < N_Q + N_KV){ qw = qw_k; qz = qz_k; sc = sc_k; r = o - N_Q;          Osec = N_KV; }
    else                    { qw = qw_v; qz = qz_v; sc = sc_v; r = o - (N_Q + N_KV); Osec = N_KV; }

    const float* wbp = w_base + (size_t)o * K_IN + (size_t)kq * 8;
    float4 wb0 = *(const float4*)(wbp);
    float4 wb1 = *(const float4*)(wbp + 4);
    float wb[8] = {wb0.x, wb0.y, wb0.z, wb0.w, wb1.x, wb1.y, wb1.z, wb1.w};

#pragma unroll
    for (int d = 0; d < N_D; d++) {
        int   q  = qw[((size_t)d * Osec + r) * KP + kq];
        int   zq = qz[(size_t)d * (Osec / 8) + (r >> 3)];
        float s  = sc[(size_t)d * Osec + r];
        float zs = (float)(((zq >> ((r & 7) * 4)) & 0xF) + 1) * s;

        ushort res[8];
#pragma unroll
        for (int j = 0; j < 8; j++) {
            float v = wb[j] + (float)((q >> (4 * j)) & 0xF) * s - zs;
            res[j] = f2bf(v);
        }
        uint4 packv;
        packv.x = pack2(res[0], res[1]); packv.y = pack2(res[2], res[3]);
        packv.z = pack2(res[4], res[5]); packv.w = pack2(res[6], res[7]);
        *(uint4*)(wall + ((size_t)d * N_OUT + o) * K_IN + (size_t)kq * 8) = packv;
    }
}

// ---------------------------------------------------------------------------
// K3: Xp[pm][k] = bf16(x[perm[pm]][k]) or 0 for padding rows.
// ---------------------------------------------------------------------------
__global__ void build_xp_kernel(const float* __restrict__ x,
                                const int* __restrict__ perm,
                                ushort* __restrict__ xp) {
    int pm = blockIdx.x;
    int c0 = blockIdx.y * 2048 + threadIdx.x * 8;
    int tok = perm[pm];
    ushort res[8];
    if (tok < 0) {
#pragma unroll
        for (int j = 0; j < 8; j++) res[j] = 0;
    } else {
        const float* src = x + (size_t)tok * K_IN + c0;
#pragma unroll
        for (int j = 0; j < 8; j++) res[j] = f2bf(src[j]);
    }
    uint4 packv;
    packv.x = pack2(res[0], res[1]); packv.y = pack2(res[2], res[3]);
    packv.z = pack2(res[4], res[5]); packv.w = pack2(res[6], res[7]);
    *(uint4*)(xp + (size_t)pm * K_IN + c0) = packv;
}

// ---------------------------------------------------------------------------
// K4: out[t][n] = bias[n] (split-K accumulators atomicAdd on top).
// ---------------------------------------------------------------------------
__global__ void init_out_kernel(const float* __restrict__ bias,
                                float* __restrict__ out) {
    int id = blockIdx.x * blockDim.x + threadIdx.x;     // [0, T*N_OUT/4)
    int n4 = id & (N_OUT / 4 - 1);                      // N_OUT/4 = 1536
    int t  = id / (N_OUT / 4);
    float4 b = *(const float4*)(bias + n4 * 4);
    *(float4*)(out + (size_t)t * N_OUT + n4 * 4) = b;
}

// ---------------------------------------------------------------------------
// K5: split-K GEMM. out[perm[m]][n] += Xp[m][kz-half] @ W_all[d(m)][n][kz-half]
// 128x128 tile, BK=64, global_load_lds(16B), XOR bank swizzle on LDS layout.
// ---------------------------------------------------------------------------
__global__ __launch_bounds__(256, 4) void gemm_kernel(
    const ushort* __restrict__ xp, const ushort* __restrict__ wall,
    const int* __restrict__ perm, const int* __restrict__ pofs,
    float* __restrict__ out) {

    __shared__ ushort As[TM * BK];   // 16 KB
    __shared__ ushort Bs[TN * BK];   // 16 KB

    int bn = blockIdx.x, bm = blockIdx.y, kz = blockIdx.z;
    int m0 = bm * TM, n0 = bn * TN;
    int ptot = pofs[N_D];
    if (m0 >= ptot) return;                       // uniform per block
    int d = 0;
    while (d < N_D - 1 && m0 >= pofs[d + 1]) d++; // tile fully inside segment d

    const ushort* wsec = wall + (size_t)d * N_OUT * K_IN;

    int tid  = threadIdx.x;
    int lane = tid & 63;
    int wv   = tid >> 6;
    int wm   = (wv & 1) * 64;
    int wn   = (wv >> 1) * 64;
    int quad = lane >> 4;
    int l16  = lane & 15;
    int xa   = l16 & 7;          // read-side swizzle term

    const float4v zero4 = {0.f, 0.f, 0.f, 0.f};
    float4v acc[4][4];
#pragma unroll
    for (int i = 0; i < 4; i++)
#pragma unroll
        for (int j = 0; j < 4; j++) acc[i][j] = zero4;

    int kbase = kz * KHALF;
    for (int k0 = kbase; k0 < kbase + KHALF; k0 += BK) {
        // stage A (Xp rows m0..m0+127) and B (W_all rows n0..n0+127), 16B/lane.
        // chunk position p holds (row = p>>3, ck = (p&7) ^ (row&7))  [XOR swizzle]
#pragma unroll
        for (int w = 0; w < 4; w++) {
            int p   = w * 256 + tid;
            int row = p >> 3;
            int ckl = (p & 7) ^ (row & 7);
            const ushort* ga = xp   + (size_t)(m0 + row) * K_IN + k0 + ckl * 8;
            const ushort* gb = wsec + (size_t)(n0 + row) * K_IN + k0 + ckl * 8;
            int base = (w * 256 + (tid & ~63)) * 8;   // wave-uniform ushort offset
            __builtin_amdgcn_global_load_lds((const __attribute__((address_space(1))) void*)ga,
                                             (__attribute__((address_space(3))) void*)(As + base), 16, 0, 0);
            __builtin_amdgcn_global_load_lds((const __attribute__((address_space(1))) void*)gb,
                                             (__attribute__((address_space(3))) void*)(Bs + base), 16, 0, 0);
        }
        __syncthreads();

#pragma unroll
        for (int kk = 0; kk < BK; kk += 32) {
            int ckb = (kk >> 3) + quad;      // 16B-chunk column wanted
            short8 a[4], b[4];
#pragma unroll
            for (int i = 0; i < 4; i++)
                a[i] = *(const short8*)(As + (wm + i * 16 + l16) * BK + (ckb ^ xa) * 8);
#pragma unroll
            for (int j = 0; j < 4; j++)
                b[j] = *(const short8*)(Bs + (wn + j * 16 + l16) * BK + (ckb ^ xa) * 8);
#pragma unroll
            for (int i = 0; i < 4; i++)
#pragma unroll
                for (int j = 0; j < 4; j++)
                    acc[i][j] = __builtin_amdgcn_mfma_f32_16x16x32_bf16(a[i], b[j], acc[i][j], 0, 0, 0);
        }
        __syncthreads();
    }

    // epilogue: C/D layout col = lane&15, row = quad*4 + reg  [m89/m91 verified]
    // bias already in out (init_out); both K-halves accumulate atomically.
#pragma unroll
    for (int i = 0; i < 4; i++) {
        int toks[4];
#pragma unroll
        for (int r = 0; r < 4; r++) toks[r] = perm[m0 + wm + i * 16 + quad * 4 + r];
#pragma unroll
        for (int j = 0; j < 4; j++) {
            int col = n0 + wn + j * 16 + l16;
#pragma unroll
            for (int r = 0; r < 4; r++) {
                int tok = toks[r];
                if (tok >= 0) atomicAdd(out + (size_t)tok * N_OUT + col, acc[i][j][r]);
            }
        }
    }
}

// ---------------------------------------------------------------------------
extern "C" void kernel_launch(void* const* d_in, const int* in_sizes, int n_in,
                              void* d_out, int out_size, void* d_ws, size_t ws_size,
                              hipStream_t stream) {
    const float* x      = (const float*)d_in[0];
    const float* w_base = (const float*)d_in[1];
    const float* bias   = (const float*)d_in[2];
    const int*   qw_q   = (const int*)d_in[3];
    const int*   qw_k   = (const int*)d_in[4];
    const int*   qw_v   = (const int*)d_in[5];
    const int*   qz_q   = (const int*)d_in[6];
    const int*   qz_k   = (const int*)d_in[7];
    const int*   qz_v   = (const int*)d_in[8];
    const float* sc_q   = (const float*)d_in[9];
    const float* sc_k   = (const float*)d_in[10];
    const float* sc_v   = (const float*)d_in[11];
    const int*   indices= (const int*)d_in[12];
    float* out = (float*)d_out;

    // workspace layout: W_all bf16 [4][6144][4096] | Xp bf16 [1536][4096] | perm | pofs
    char* ws = (char*)d_ws;
    ushort* wall = (ushort*)ws;
    size_t wall_bytes = (size_t)N_D * N_OUT * K_IN * 2;          // 201326592
    ushort* xp = (ushort*)(ws + wall_bytes);
    size_t xp_bytes = (size_t)PM_MAX * K_IN * 2;                  // 12582912
    int* perm = (int*)(ws + wall_bytes + xp_bytes);
    int* pofs = perm + PM_MAX;

    build_perm_kernel<<<1, 256, 0, stream>>>(indices, perm, pofs);
    dequant_wall_kernel<<<(N_OUT * KP) / 256, 256, 0, stream>>>(
        w_base, qw_q, qw_k, qw_v, qz_q, qz_k, qz_v, sc_q, sc_k, sc_v, wall);
    build_xp_kernel<<<dim3(PM_MAX, 2), 256, 0, stream>>>(x, perm, xp);
    init_out_kernel<<<(T_TOK * N_OUT / 4) / 256, 256, 0, stream>>>(bias, out);
    gemm_kernel<<<dim3(NT, MT, KSPLIT), 256, 0, stream>>>(xp, wall, perm, pofs, out);
}

// Round 3
// 367.930 us; speedup vs baseline: 1.1045x; 1.0244x over previous
//
#include <hip/hip_runtime.h>
#include <stdint.h>

// Problem constants (from reference setup_inputs)
#define T_TOK 1024
#define K_IN  4096
#define N_OUT 6144
#define N_Q   4096
#define N_KV  1024
#define N_D   4
#define KP    512          // K_IN/8 packed int32 per row

// GEMM tiling
#define TM 128
#define TN 128
#define BK 64
#define KSPLIT 2
#define KHALF (K_IN / KSPLIT)   // 2048
#define NSTEPS (KHALF / BK)     // 32
#define PM_MAX 1536        // >= 1024 + 4*127 rounded up; fixed grid bound
#define MT (PM_MAX/TM)     // 12
#define NT (N_OUT/TN)      // 48
#define NBLK (NT * MT * KSPLIT) // 1152

typedef __attribute__((ext_vector_type(8)))  short  short8;   // 8 x bf16 (4 VGPR) MFMA A/B frag
typedef __attribute__((ext_vector_type(4)))  float  float4v;  // MFMA C/D frag
typedef __attribute__((ext_vector_type(4)))  float  f32x4;
typedef __attribute__((ext_vector_type(4)))  uint   u32x4;

__device__ __forceinline__ ushort f2bf(float f) {
    uint32_t u = __float_as_uint(f);
    u = (u + 0x7FFFu + ((u >> 16) & 1u)) >> 16;   // RNE
    return (ushort)u;
}
__device__ __forceinline__ uint pack2(ushort a, ushort b) {
    return (uint)a | ((uint)b << 16);
}

// ---------------------------------------------------------------------------
// K1: group tokens by adapter. perm[PM_MAX] = token index or -1 (padding);
// pofs[d] = padded segment starts (multiples of TM), pofs[N_D] = padded total.
// ---------------------------------------------------------------------------
__global__ void build_perm_kernel(const int* __restrict__ indices,
                                  int* __restrict__ perm,
                                  int* __restrict__ pofs) {
    __shared__ int cnt[N_D], cur[N_D], ps[N_D + 1];
    int tid = threadIdx.x;
    if (tid < N_D) { cnt[tid] = 0; cur[tid] = 0; }
    __syncthreads();
    for (int t = tid; t < T_TOK; t += blockDim.x) atomicAdd(&cnt[indices[t]], 1);
    for (int p = tid; p < PM_MAX; p += blockDim.x) perm[p] = -1;
    __syncthreads();
    if (tid == 0) {
        int run = 0;
        for (int d = 0; d < N_D; d++) { ps[d] = run; run += ((cnt[d] + TM - 1) / TM) * TM; }
        ps[N_D] = run;
        for (int d = 0; d <= N_D; d++) pofs[d] = ps[d];
    }
    __syncthreads();
    for (int t = tid; t < T_TOK; t += blockDim.x) {
        int d = indices[t];
        int r = atomicAdd(&cur[d], 1);
        perm[ps[d] + r] = t;   // slot order arbitrary; per-token result independent of slot
    }
}

// ---------------------------------------------------------------------------
// K2: W_all[d][o][k] = bf16( w_base[o][k] + (nib(qw)- (nib(qz)+1)) * scale )
// One thread per (o, kq) handles ALL 4 adapters: w_base read ONCE.
// Single-use inputs (w_base, qw) loaded nontemporal so the 201 MB wall output
// stays LLC-resident for the GEMM's B-stream.
// ---------------------------------------------------------------------------
__global__ void dequant_wall_kernel(const float* __restrict__ w_base,
                                    const int* __restrict__ qw_q, const int* __restrict__ qw_k, const int* __restrict__ qw_v,
                                    const int* __restrict__ qz_q, const int* __restrict__ qz_k, const int* __restrict__ qz_v,
                                    const float* __restrict__ sc_q, const float* __restrict__ sc_k, const float* __restrict__ sc_v,
                                    ushort* __restrict__ wall) {
    int id  = blockIdx.x * blockDim.x + threadIdx.x;   // [0, N_OUT*KP)
    int kq  = id & (KP - 1);
    int o   = id >> 9;          // KP = 512; block-uniform (256 | 512)

    const int* qw; const int* qz; const float* sc; int r, Osec;
    if (o < N_Q)            { qw = qw_q; qz = qz_q; sc = sc_q; r = o;                Osec = N_Q;  }
    else if (o < N_Q + N_KV){ qw = qw_k; qz = qz_k; sc = sc_k; r = o - N_Q;          Osec = N_KV; }
    else                    { qw = qw_v; qz = qz_v; sc = sc_v; r = o - (N_Q + N_KV); Osec = N_KV; }

    const f32x4* wbp = (const f32x4*)(w_base + (size_t)o * K_IN + (size_t)kq * 8);
    f32x4 wb0 = __builtin_nontemporal_load(wbp);
    f32x4 wb1 = __builtin_nontemporal_load(wbp + 1);
    float wb[8] = {wb0.x, wb0.y, wb0.z, wb0.w, wb1.x, wb1.y, wb1.z, wb1.w};

#pragma unroll
    for (int d = 0; d < N_D; d++) {
        int   q  = __builtin_nontemporal_load(qw + ((size_t)d * Osec + r) * KP + kq);
        int   zq = qz[(size_t)d * (Osec / 8) + (r >> 3)];
        float s  = sc[(size_t)d * Osec + r];
        float zs = (float)(((zq >> ((r & 7) * 4)) & 0xF) + 1) * s;

        ushort res[8];
#pragma unroll
        for (int j = 0; j < 8; j++) {
            float v = wb[j] + (float)((q >> (4 * j)) & 0xF) * s - zs;
            res[j] = f2bf(v);
        }
        u32x4 packv;
        packv.x = pack2(res[0], res[1]); packv.y = pack2(res[2], res[3]);
        packv.z = pack2(res[4], res[5]); packv.w = pack2(res[6], res[7]);
        *(u32x4*)(wall + ((size_t)d * N_OUT + o) * K_IN + (size_t)kq * 8) = packv;
    }
}

// ---------------------------------------------------------------------------
// K3: Xp[pm][k] = bf16(x[perm[pm]][k]) or 0 for padding rows.
// ---------------------------------------------------------------------------
__global__ void build_xp_kernel(const float* __restrict__ x,
                                const int* __restrict__ perm,
                                ushort* __restrict__ xp) {
    int pm = blockIdx.x;
    int c0 = blockIdx.y * 2048 + threadIdx.x * 8;
    int tok = perm[pm];
    ushort res[8];
    if (tok < 0) {
#pragma unroll
        for (int j = 0; j < 8; j++) res[j] = 0;
    } else {
        const f32x4* src = (const f32x4*)(x + (size_t)tok * K_IN + c0);
        f32x4 a = __builtin_nontemporal_load(src);
        f32x4 b = __builtin_nontemporal_load(src + 1);
        float v[8] = {a.x, a.y, a.z, a.w, b.x, b.y, b.z, b.w};
#pragma unroll
        for (int j = 0; j < 8; j++) res[j] = f2bf(v[j]);
    }
    u32x4 packv;
    packv.x = pack2(res[0], res[1]); packv.y = pack2(res[2], res[3]);
    packv.z = pack2(res[4], res[5]); packv.w = pack2(res[6], res[7]);
    *(u32x4*)(xp + (size_t)pm * K_IN + c0) = packv;
}

// ---------------------------------------------------------------------------
// K4: out[t][n] = bias[n] (split-K accumulators atomicAdd on top).
// ---------------------------------------------------------------------------
__global__ void init_out_kernel(const float* __restrict__ bias,
                                float* __restrict__ out) {
    int id = blockIdx.x * blockDim.x + threadIdx.x;     // [0, T*N_OUT/4)
    int n4 = id & (N_OUT / 4 - 1);                      // N_OUT/4 = 1536
    int t  = id / (N_OUT / 4);
    float4 b = *(const float4*)(bias + n4 * 4);
    *(float4*)(out + (size_t)t * N_OUT + n4 * 4) = b;
}

// ---------------------------------------------------------------------------
// K5: split-K GEMM, double-buffered LDS.
// out[perm[m]][n] += Xp[m][kz-half] @ W_all[d(m)][n][kz-half]
// 128x128 tile, BK=64, global_load_lds(16B), XOR bank swizzle, 2-stage dbuf
// so the HBM-latency B-stream overlaps MFMA. 1-D grid with XCD pinning:
// all blocks of one bn land on lin%8 == bn%8 -> same XCD L2 shares B slice.
// ---------------------------------------------------------------------------
__global__ __launch_bounds__(256, 2) void gemm_kernel(
    const ushort* __restrict__ xp, const ushort* __restrict__ wall,
    const int* __restrict__ perm, const int* __restrict__ pofs,
    float* __restrict__ out) {

    __shared__ ushort As[2][TM * BK];   // 2 x 16 KB
    __shared__ ushort Bs[2][TN * BK];   // 2 x 16 KB

    // XCD-pinned decode: lin = 8*(bq*24 + j) + low3; bn = bq*8+low3
    int lin  = blockIdx.x;
    int low3 = lin & 7, rest = lin >> 3;
    int j    = rest % 24, bq = rest / 24;
    int bn   = bq * 8 + low3;
    int bm   = j % MT, kz = j / MT;

    int m0 = bm * TM, n0 = bn * TN;
    int ptot = pofs[N_D];
    if (m0 >= ptot) return;                       // uniform per block
    int d = 0;
    while (d < N_D - 1 && m0 >= pofs[d + 1]) d++; // tile fully inside segment d

    const ushort* wsec = wall + (size_t)d * N_OUT * K_IN;

    int tid  = threadIdx.x;
    int lane = tid & 63;
    int wv   = tid >> 6;
    int wm   = (wv & 1) * 64;
    int wn   = (wv >> 1) * 64;
    int quad = lane >> 4;
    int l16  = lane & 15;
    int xa   = l16 & 7;          // read-side swizzle term

    const float4v zero4 = {0.f, 0.f, 0.f, 0.f};
    float4v acc[4][4];
#pragma unroll
    for (int i = 0; i < 4; i++)
#pragma unroll
        for (int jj = 0; jj < 4; jj++) acc[i][jj] = zero4;

    // stage one BK-tile (A+B) into the given LDS buffers; 16B/lane, XOR swizzle
    auto stage = [&](ushort* dstA, ushort* dstB, int k0) {
#pragma unroll
        for (int w = 0; w < 4; w++) {
            int p   = w * 256 + tid;
            int row = p >> 3;
            int ckl = (p & 7) ^ (row & 7);
            const ushort* ga = xp   + (size_t)(m0 + row) * K_IN + k0 + ckl * 8;
            const ushort* gb = wsec + (size_t)(n0 + row) * K_IN + k0 + ckl * 8;
            int base = (w * 256 + (tid & ~63)) * 8;   // wave-uniform ushort offset
            __builtin_amdgcn_global_load_lds((const __attribute__((address_space(1))) void*)ga,
                                             (__attribute__((address_space(3))) void*)(dstA + base), 16, 0, 0);
            __builtin_amdgcn_global_load_lds((const __attribute__((address_space(1))) void*)gb,
                                             (__attribute__((address_space(3))) void*)(dstB + base), 16, 0, 0);
        }
    };

    int kbase = kz * KHALF;
    int buf = 0;
    stage(As[0], Bs[0], kbase);
    __syncthreads();

    for (int s = 0; s < NSTEPS; s++) {
        if (s + 1 < NSTEPS) stage(As[1 - buf], Bs[1 - buf], kbase + (s + 1) * BK);

        const ushort* Ab = As[buf];
        const ushort* Bb = Bs[buf];
#pragma unroll
        for (int kk = 0; kk < BK; kk += 32) {
            int ckb = (kk >> 3) + quad;      // 16B-chunk column wanted
            short8 a[4], b[4];
#pragma unroll
            for (int i = 0; i < 4; i++)
                a[i] = *(const short8*)(Ab + (wm + i * 16 + l16) * BK + (ckb ^ xa) * 8);
#pragma unroll
            for (int jj = 0; jj < 4; jj++)
                b[jj] = *(const short8*)(Bb + (wn + jj * 16 + l16) * BK + (ckb ^ xa) * 8);
#pragma unroll
            for (int i = 0; i < 4; i++)
#pragma unroll
                for (int jj = 0; jj < 4; jj++)
                    acc[i][jj] = __builtin_amdgcn_mfma_f32_16x16x32_bf16(a[i], b[jj], acc[i][jj], 0, 0, 0);
        }
        __syncthreads();   // drains next tile's loads + protects buf for re-stage
        buf ^= 1;
    }

    // epilogue: C/D layout col = lane&15, row = quad*4 + reg  [m89/m91 verified]
    // bias already in out (init_out); both K-halves accumulate atomically.
#pragma unroll
    for (int i = 0; i < 4; i++) {
        int toks[4];
#pragma unroll
        for (int r = 0; r < 4; r++) toks[r] = perm[m0 + wm + i * 16 + quad * 4 + r];
#pragma unroll
        for (int jj = 0; jj < 4; jj++) {
            int col = n0 + wn + jj * 16 + l16;
#pragma unroll
            for (int r = 0; r < 4; r++) {
                int tok = toks[r];
                if (tok >= 0) atomicAdd(out + (size_t)tok * N_OUT + col, acc[i][jj][r]);
            }
        }
    }
}

// ---------------------------------------------------------------------------
extern "C" void kernel_launch(void* const* d_in, const int* in_sizes, int n_in,
                              void* d_out, int out_size, void* d_ws, size_t ws_size,
                              hipStream_t stream) {
    const float* x      = (const float*)d_in[0];
    const float* w_base = (const float*)d_in[1];
    const float* bias   = (const float*)d_in[2];
    const int*   qw_q   = (const int*)d_in[3];
    const int*   qw_k   = (const int*)d_in[4];
    const int*   qw_v   = (const int*)d_in[5];
    const int*   qz_q   = (const int*)d_in[6];
    const int*   qz_k   = (const int*)d_in[7];
    const int*   qz_v   = (const int*)d_in[8];
    const float* sc_q   = (const float*)d_in[9];
    const float* sc_k   = (const float*)d_in[10];
    const float* sc_v   = (const float*)d_in[11];
    const int*   indices= (const int*)d_in[12];
    float* out = (float*)d_out;

    // workspace layout: W_all bf16 [4][6144][4096] | Xp bf16 [1536][4096] | perm | pofs
    char* ws = (char*)d_ws;
    ushort* wall = (ushort*)ws;
    size_t wall_bytes = (size_t)N_D * N_OUT * K_IN * 2;          // 201326592
    ushort* xp = (ushort*)(ws + wall_bytes);
    size_t xp_bytes = (size_t)PM_MAX * K_IN * 2;                  // 12582912
    int* perm = (int*)(ws + wall_bytes + xp_bytes);
    int* pofs = perm + PM_MAX;

    build_perm_kernel<<<1, 256, 0, stream>>>(indices, perm, pofs);
    dequant_wall_kernel<<<(N_OUT * KP) / 256, 256, 0, stream>>>(
        w_base, qw_q, qw_k, qw_v, qz_q, qz_k, qz_v, sc_q, sc_k, sc_v, wall);
    build_xp_kernel<<<dim3(PM_MAX, 2), 256, 0, stream>>>(x, perm, xp);
    init_out_kernel<<<(T_TOK * N_OUT / 4) / 256, 256, 0, stream>>>(bias, out);
    gemm_kernel<<<NBLK, 256, 0, stream>>>(xp, wall, perm, pofs, out);
}